// Round 1
// baseline (142.474 us; speedup 1.0000x reference)
//
#include <hip/hip_runtime.h>
#include <math.h>

// Problem constants (from setup_inputs): H=1024, B=32, S=4096, all f32.
constexpr int H = 1024;
constexpr int B = 32;
constexpr int S = 4096;
constexpr int STILE = 64;   // s-rows per block in energies kernel

// ---------------------------------------------------------------------------
// Kernel 1: v[b,h] = sum_g hidden[b,g] * W[g,h]
// Grid: B*4 blocks of 256 threads; one thread per (b,h).
// W column reads are coalesced (consecutive h across threads); W (4 MiB) is
// L2-resident so the 32x re-read costs ~4 us of L2 traffic.
// ---------------------------------------------------------------------------
__global__ __launch_bounds__(256) void compute_v_kernel(
    const float* __restrict__ hidden, const float* __restrict__ W,
    float* __restrict__ v)
{
    const int h = ((blockIdx.x & 3) << 8) + threadIdx.x;
    const int b = blockIdx.x >> 2;
    const float* __restrict__ hb = hidden + b * H;
    float a0 = 0.f, a1 = 0.f, a2 = 0.f, a3 = 0.f;
    for (int g = 0; g < H; g += 4) {
        a0 = fmaf(hb[g + 0], W[(g + 0) * H + h], a0);
        a1 = fmaf(hb[g + 1], W[(g + 1) * H + h], a1);
        a2 = fmaf(hb[g + 2], W[(g + 2) * H + h], a2);
        a3 = fmaf(hb[g + 3], W[(g + 3) * H + h], a3);
    }
    v[b * H + h] = (a0 + a1) + (a2 + a3);
}

// ---------------------------------------------------------------------------
// Kernel 2: energies[b,s] = v[b,:] . enc[s,b,:]   (bias term cancels in
// softmax via shift invariance). One wave per (s,b) row; float4 loads
// (1 KiB per wave-instruction); v[b,:] staged once per block in LDS.
// Writes energies directly into d_out (same size as final output).
// ---------------------------------------------------------------------------
__global__ __launch_bounds__(256) void energies_kernel(
    const float* __restrict__ enc, const float* __restrict__ v,
    float* __restrict__ energies)
{
    constexpr int tilesPerB = S / STILE;              // 64
    const int b  = blockIdx.x / tilesPerB;
    const int s0 = (blockIdx.x % tilesPerB) * STILE;

    __shared__ float4 vs[H / 4];
    const float4* __restrict__ vb = (const float4*)(v + b * H);
    for (int i = threadIdx.x; i < H / 4; i += 256) vs[i] = vb[i];
    __syncthreads();

    const int wave = threadIdx.x >> 6;
    const int lane = threadIdx.x & 63;

    for (int si = wave; si < STILE; si += 4) {
        const int s = s0 + si;
        const float4* __restrict__ row =
            (const float4*)(enc + ((size_t)s * B + b) * H);
        float acc = 0.f;
        #pragma unroll
        for (int it = 0; it < 4; ++it) {
            float4 e = row[it * 64 + lane];
            float4 w = vs[it * 64 + lane];
            acc = fmaf(e.x, w.x, acc);
            acc = fmaf(e.y, w.y, acc);
            acc = fmaf(e.z, w.z, acc);
            acc = fmaf(e.w, w.w, acc);
        }
        #pragma unroll
        for (int off = 32; off > 0; off >>= 1)
            acc += __shfl_xor(acc, off, 64);
        if (lane == 0) energies[b * S + s] = acc;
    }
}

// ---------------------------------------------------------------------------
// Kernel 3: in-place row softmax over d_out[b, 0, :]. One block per b;
// row cached in 16 registers/thread so HBM traffic is 1 read + 1 write.
// ---------------------------------------------------------------------------
__global__ __launch_bounds__(256) void softmax_kernel(float* __restrict__ out)
{
    const int b = blockIdx.x;
    float* __restrict__ row = out + (size_t)b * S;
    __shared__ float redm[4];
    __shared__ float reds[4];
    const int wave = threadIdx.x >> 6;
    const int lane = threadIdx.x & 63;

    float vals[S / 256];                 // 16 registers
    float m = -INFINITY;
    #pragma unroll
    for (int k = 0; k < S / 256; ++k) {
        vals[k] = row[threadIdx.x + k * 256];
        m = fmaxf(m, vals[k]);
    }
    #pragma unroll
    for (int off = 32; off > 0; off >>= 1)
        m = fmaxf(m, __shfl_xor(m, off, 64));
    if (lane == 0) redm[wave] = m;
    __syncthreads();
    m = fmaxf(fmaxf(redm[0], redm[1]), fmaxf(redm[2], redm[3]));

    float ssum = 0.f;
    #pragma unroll
    for (int k = 0; k < S / 256; ++k) {
        vals[k] = __expf(vals[k] - m);
        ssum += vals[k];
    }
    #pragma unroll
    for (int off = 32; off > 0; off >>= 1)
        ssum += __shfl_xor(ssum, off, 64);
    if (lane == 0) reds[wave] = ssum;
    __syncthreads();
    const float inv = 1.0f / ((reds[0] + reds[1]) + (reds[2] + reds[3]));
    #pragma unroll
    for (int k = 0; k < S / 256; ++k)
        row[threadIdx.x + k * 256] = vals[k] * inv;
}

extern "C" void kernel_launch(void* const* d_in, const int* in_sizes, int n_in,
                              void* d_out, int out_size, void* d_ws, size_t ws_size,
                              hipStream_t stream) {
    const float* hidden = (const float*)d_in[0];   // [1, B, H]
    const float* enc    = (const float*)d_in[1];   // [S, B, H]
    const float* W      = (const float*)d_in[2];   // [H, H]
    // d_in[3] = attn_b: contributes a per-b constant to energies -> cancels
    // exactly under softmax (shift invariance); intentionally unused.
    float* out = (float*)d_out;                    // [B, 1, S] == B*S floats
    float* v   = (float*)d_ws;                     // B*H floats = 512 KiB

    compute_v_kernel<<<dim3(B * 4), dim3(256), 0, stream>>>(hidden, W, v);
    energies_kernel<<<dim3(B * (S / STILE)), dim3(256), 0, stream>>>(enc, v, out);
    softmax_kernel<<<dim3(B), dim3(256), 0, stream>>>(out);
}